// Round 15
// baseline (331.571 us; speedup 1.0000x reference)
//
#include <hip/hip_runtime.h>

typedef unsigned short ushort_t;
typedef __bf16 bf16x8 __attribute__((ext_vector_type(8)));
typedef float f32x4 __attribute__((ext_vector_type(4)));
typedef short short8 __attribute__((ext_vector_type(8)));
typedef short short4v __attribute__((ext_vector_type(4)));

#define SBAR()   asm volatile("s_barrier" ::: "memory")
#define WAITV0() asm volatile("s_waitcnt vmcnt(0)" ::: "memory")
#define WAITV4() asm volatile("s_waitcnt vmcnt(4)" ::: "memory")
#define WAITV8() asm volatile("s_waitcnt vmcnt(8)" ::: "memory")

__device__ __forceinline__ float bf2f(unsigned short u) {
    union { unsigned int i; float f; } v; v.i = ((unsigned int)u) << 16; return v.f;
}
__device__ __forceinline__ unsigned short f2bf(float f) {
    union { float f; unsigned int i; } v; v.f = f;
    unsigned int r = v.i + 0x7fffu + ((v.i >> 16) & 1u);
    return (unsigned short)(r >> 16);
}
__device__ __forceinline__ float sigm(float x) { return 1.0f / (1.0f + __expf(-x)); }

__device__ __forceinline__ void async_copy16(const ushort_t* src, ushort_t* dst_lds) {
    __builtin_amdgcn_global_load_lds(
        (const __attribute__((address_space(1))) void*)src,
        (__attribute__((address_space(3))) void*)dst_lds,
        16, 0, 0);
}

// ---- merged f32->bf16 conversion: inputs (q,k,v -> X) + params (5W+5b+ts -> Wb) ----
#define WSEG 589824           // 768*768
#define NWALL 2949120         // 5*WSEG
#define NTOT 2953728          // + 6*768
#define PERT 12582912ll       // 16384*768
#define INBLK 18432           // 3*PERT/8/256
__global__ __launch_bounds__(256)
void convert_all(const float* __restrict__ qi, const float* __restrict__ ki,
                 const float* __restrict__ vi,
                 const float* __restrict__ Wq, const float* __restrict__ Wk,
                 const float* __restrict__ Wv, const float* __restrict__ Wg1,
                 const float* __restrict__ Wg2, const float* __restrict__ bq,
                 const float* __restrict__ bk, const float* __restrict__ bv,
                 const float* __restrict__ bg1, const float* __restrict__ bg2,
                 const float* __restrict__ ts,
                 ushort_t* __restrict__ X, ushort_t* __restrict__ Wb)
{
    if (blockIdx.x < INBLK) {
        long long i = ((long long)blockIdx.x * 256 + threadIdx.x) * 8;
        const float* src; long long off;
        if (i < PERT)          { src = qi; off = i; }
        else if (i < 2 * PERT) { src = ki; off = i - PERT; }
        else                   { src = vi; off = i - 2 * PERT; }
        float4 a = *(const float4*)(src + off);
        float4 b = *(const float4*)(src + off + 4);
        short8 o;
        o[0] = (short)f2bf(a.x); o[1] = (short)f2bf(a.y); o[2] = (short)f2bf(a.z); o[3] = (short)f2bf(a.w);
        o[4] = (short)f2bf(b.x); o[5] = (short)f2bf(b.y); o[6] = (short)f2bf(b.z); o[7] = (short)f2bf(b.w);
        *(short8*)(X + i) = o;
    } else {
        int e = ((blockIdx.x - INBLK) * 256 + threadIdx.x) * 8;
        if (e >= NTOT) return;
        const float* src; int off;
        if (e < NWALL) {
            int wi = e / WSEG; off = e - wi * WSEG;
            src = (wi == 0) ? Wq : (wi == 1) ? Wk : (wi == 2) ? Wv : (wi == 3) ? Wg1 : Wg2;
        } else {
            int j = e - NWALL; int bi = j / 768; off = j - bi * 768;
            src = (bi == 0) ? bq : (bi == 1) ? bk : (bi == 2) ? bv : (bi == 3) ? bg1 : (bi == 4) ? bg2 : ts;
        }
        float4 a = *(const float4*)(src + off);
        float4 b = *(const float4*)(src + off + 4);
        short8 o;
        o[0] = (short)f2bf(a.x); o[1] = (short)f2bf(a.y); o[2] = (short)f2bf(a.z); o[3] = (short)f2bf(a.w);
        o[4] = (short)f2bf(b.x); o[5] = (short)f2bf(b.y); o[6] = (short)f2bf(b.z); o[7] = (short)f2bf(b.w);
        *(short8*)(Wb + e) = o;
    }
}

// C[M,N] = A[M,K] @ B[N,K]^T (+ epilogue), optionally batched (M = rows per batch).
// All-bf16 operands via global_load_lds; 3-buffer 2-deep counted-vmcnt pipeline, raw s_barrier.
// CF32: f32 store. QKV: gridDim.z=3; bz=0/1 -> Cv+bz*batchC (row-major), bz=2 -> Cv2 in
// TRANSPOSED per-batch layout vT[z][col][row] via LDS-staged coalesced write.
// EPI: 0=plain, 1=+bias, 3=+bias+relu, 4=gate sigmoid(sigmoid(x+bias))*aux*ts,
//      5=exp(x*scale) + per-block row partial sums -> psum_out[bz*M+row][gridDim.x],
//      7=multiply by 1/rowsum computed in-prologue from psum_out (16 partials/row)
// Requires gridDim.x*gridDim.y*gridDim.z % 8 == 0, K%32==0, K>=64.
template<int EPI, int CF32, int QKV>
__global__ __launch_bounds__(256, 2)
void gemm_bt(const ushort_t* __restrict__ A, const ushort_t* __restrict__ B,
             void* __restrict__ Cv, void* __restrict__ Cv2,
             const ushort_t* __restrict__ bias,
             const ushort_t* __restrict__ aux, const ushort_t* __restrict__ ts,
             float* __restrict__ psum_out,
             int M, int N, int K, float scale,
             long long batchA, long long batchB, long long batchC)
{
    // 48KB staging block; reused by the QKV bz==2 epilogue as a [128 col][136] bf16 tile
    __shared__ __align__(16) ushort_t LDSbuf[24576];
    __shared__ float rsmx[256];
    ushort_t* Asb = LDSbuf;            // 3 x 4096 ushorts
    ushort_t* Bsb = LDSbuf + 12288;    // 3 x 4096 ushorts
    const int tid  = threadIdx.x;
    const int lane = tid & 63;
    const int wave = tid >> 6;
    const int wr = wave >> 1, wc = wave & 1;

    // XCD-aware bijective swizzle over the full flat grid (nwg % 8 == 0)
    const int gx = gridDim.x, gy = gridDim.y;
    const int nwg = gx * gy * gridDim.z;
    int fid = (blockIdx.z * gy + blockIdx.y) * gx + blockIdx.x;
    fid = (fid & 7) * (nwg >> 3) + (fid >> 3);
    const int bz  = fid / (gx * gy);
    const int rem = fid - bz * (gx * gy);
    const int by  = rem / gx;
    const int bx  = rem - by * gx;
    const int row0 = by * 128;
    const int col0 = bx * 128;

    // EPI=7: per-block rinv for its 128 rows from psums (16 = scores gridDim.x = S/128).
    if (EPI == 7) {
        if (tid < 128) {
            const float* pp = psum_out + ((size_t)bz * M + row0 + tid) * 16;
            float s = 0.f;
            #pragma unroll
            for (int i = 0; i < 16; ++i) s += pp[i];
            rsmx[tid] = 1.0f / s;
        }
        __syncthreads();
    }

    f32x4 acc[4][4] = {};

    // staging: 256 threads x 16B = 64 rows of 32 bf16 per inst
    const int srow = tid >> 2;
    const int scol = (tid & 3) * 8;
    const ushort_t* ga0 = A + batchA * bz + (size_t)(row0 + srow) * K + scol;
    const ushort_t* gb0 = B + batchB * bz + (size_t)(col0 + srow) * K + scol;

    const int kop  = (lane >> 4) * 8;
    const int arow = wr * 64 + (lane & 15);
    const int brow = wc * 64 + (lane & 15);

    const int NT = K >> 5;

#define STAGE4(T, BUF) do { const int kk_ = (T) * 32; \
    async_copy16(ga0 + kk_,                  Asb + (BUF) * 4096 + tid * 8); \
    async_copy16(ga0 + (size_t)64 * K + kk_, Asb + (BUF) * 4096 + 2048 + tid * 8); \
    async_copy16(gb0 + kk_,                  Bsb + (BUF) * 4096 + tid * 8); \
    async_copy16(gb0 + (size_t)64 * K + kk_, Bsb + (BUF) * 4096 + 2048 + tid * 8); \
} while (0)

    STAGE4(0, 0);
    STAGE4(1, 1);

    int cur = 0;
    for (int t = 0; t < NT; ++t) {
        if (t + 2 < NT) {
            int nb = cur + 2; if (nb >= 3) nb -= 3;
            STAGE4(t + 2, nb);
            WAITV8();   // tile t landed; tiles t+1, t+2 (8 loads) in flight
        } else if (t + 1 < NT) {
            WAITV4();   // tile t landed; tile t+1 in flight
        } else {
            WAITV0();
        }
        SBAR();
        const ushort_t* Ac = Asb + cur * 4096;
        const ushort_t* Bc = Bsb + cur * 4096;
        bf16x8 af[4], bfr[4];
        #pragma unroll
        for (int m = 0; m < 4; ++m)
            af[m] = *(const bf16x8*)(Ac + (arow + m * 16) * 32 + kop);
        #pragma unroll
        for (int n = 0; n < 4; ++n)
            bfr[n] = *(const bf16x8*)(Bc + (brow + n * 16) * 32 + kop);
        #pragma unroll
        for (int m = 0; m < 4; ++m)
            #pragma unroll
            for (int n = 0; n < 4; ++n)
                acc[m][n] = __builtin_amdgcn_mfma_f32_16x16x32_bf16(af[m], bfr[n], acc[m][n], 0, 0, 0);
        SBAR();
        ++cur; if (cur >= 3) cur = 0;
    }
#undef STAGE4

    // epilogue: C/D layout col=lane&15, row=(lane>>4)*4+reg
    const int r0 = row0 + wr * 64 + (lane >> 4) * 4;
    const int c0 = col0 + wc * 64 + (lane & 15);

    float rv[4][4];
    if (EPI == 7) {
        #pragma unroll
        for (int m = 0; m < 4; ++m)
            #pragma unroll
            for (int r = 0; r < 4; ++r)
                rv[m][r] = rsmx[wr * 64 + m * 16 + (lane >> 4) * 4 + r];
    }
    float rsum[4][4] = {};

    if (QKV && bz == 2) {
        // Stage v-tile transposed in LDS (vt[col][136], 16B-aligned rows), then stream
        // coalesced 128B column-halves to vT[z][col][row] (z = row>>11).
        ushort_t* vt = LDSbuf;       // 128*136 = 17408 ushorts <= 24576
        const int lr0 = wr * 64 + (lane >> 4) * 4;   // local row of acc[.][.][0]
        const int lc0 = wc * 64 + (lane & 15);       // local col
        #pragma unroll
        for (int m = 0; m < 4; ++m) {
            const int lr = lr0 + m * 16;
            #pragma unroll
            for (int n = 0; n < 4; ++n) {
                const int lc = lc0 + n * 16;
                const float bv_ = bf2f(bias[2 * 768 + lc + col0]);
                short4v o;
                #pragma unroll
                for (int r = 0; r < 4; ++r)
                    o[r] = (short)f2bf(acc[m][n][r] + bv_);
                *(short4v*)(vt + lc * 136 + lr) = o;
            }
        }
        __syncthreads();
        const int c_l = tid >> 1;                 // 0..127
        const int r_l = (tid & 1) * 64;           // 0 or 64
        ushort_t* dst = (ushort_t*)Cv2 + ((size_t)(row0 >> 11)) * 1572864ll
                        + (size_t)(col0 + c_l) * 2048 + ((row0 & 2047) + r_l);
        const ushort_t* srcv = vt + c_l * 136 + r_l;
        #pragma unroll
        for (int j = 0; j < 8; ++j)
            *(short8*)(dst + j * 8) = *(const short8*)(srcv + j * 8);
        return;
    }

    ushort_t* Cb = (ushort_t*)Cv + batchC * bz;
    float* Cf = (float*)Cv;
    #pragma unroll
    for (int m = 0; m < 4; ++m) {
        #pragma unroll
        for (int n = 0; n < 4; ++n) {
            const int col = c0 + n * 16;
            #pragma unroll
            for (int r = 0; r < 4; ++r) {
                const int row = r0 + m * 16 + r;
                float val = acc[m][n][r];
                if (EPI == 1) {
                    val += bf2f(bias[(QKV ? bz * 768 : 0) + col]);
                } else if (EPI == 3) {
                    val += bf2f(bias[col]);
                    val = fmaxf(val, 0.0f);
                } else if (EPI == 4) {
                    val += bf2f(bias[col]);
                    float g  = sigm(val);
                    float gg = sigm(g);
                    val = gg * bf2f(aux[(size_t)row * N + col]) * bf2f(ts[col]);
                } else if (EPI == 5) {
                    val = __expf(val * scale);
                    rsum[m][r] += val;
                } else if (EPI == 7) {
                    val *= rv[m][r];
                }
                if (CF32) Cf[(size_t)row * N + col] = val;
                else      Cb[(size_t)row * N + col] = f2bf(val);
            }
        }
    }

    if (EPI == 5) {
        // reduce over the 16 lanes holding the wave's 16-col groups (lane bits 0..3)
        #pragma unroll
        for (int m = 0; m < 4; ++m)
            #pragma unroll
            for (int r = 0; r < 4; ++r) {
                float s = rsum[m][r];
                s += __shfl_xor(s, 1);
                s += __shfl_xor(s, 2);
                s += __shfl_xor(s, 4);
                s += __shfl_xor(s, 8);
                rsum[m][r] = s;
            }
        if ((lane & 15) == 0) {
            const int quad = lane >> 4;
            #pragma unroll
            for (int m = 0; m < 4; ++m)
                #pragma unroll
                for (int r = 0; r < 4; ++r)
                    rsmx[(wr * 64 + m * 16 + quad * 4 + r) * 2 + wc] = rsum[m][r];
        }
        __syncthreads();
        if (tid < 128) {
            float s = rsmx[tid * 2] + rsmx[tid * 2 + 1];
            psum_out[((size_t)bz * M + row0 + tid) * gx + bx] = s;
        }
    }
}

extern "C" void kernel_launch(void* const* d_in, const int* in_sizes, int n_in,
                              void* d_out, int out_size, void* d_ws, size_t ws_size,
                              hipStream_t stream)
{
    (void)in_sizes; (void)n_in; (void)out_size; (void)ws_size;
    const float* query = (const float*)d_in[0];
    const float* key_  = (const float*)d_in[1];
    const float* value = (const float*)d_in[2];
    const float* Wq  = (const float*)d_in[3];
    const float* bq  = (const float*)d_in[4];
    const float* Wk  = (const float*)d_in[5];
    const float* bk  = (const float*)d_in[6];
    const float* Wv  = (const float*)d_in[7];
    const float* bv  = (const float*)d_in[8];
    const float* Wg1 = (const float*)d_in[9];
    const float* bg1 = (const float*)d_in[10];
    const float* Wg2 = (const float*)d_in[11];
    const float* bg2 = (const float*)d_in[12];
    const float* tsc = (const float*)d_in[13];

    const int S = 2048, D = 768, Bc = 8;
    const int MS = Bc * S;                     // 16384
    const long long SD = (long long)S * D;     // 1,572,864
    const long long SS = (long long)S * S;     // 4,194,304
    const long long MSD = (long long)MS * D;   // 12,582,912

    // ws layout (bytes):
    //   q/att @0 (24MiB) | k/h @24MiB | X @48MiB (72MiB) | P @72MiB (64MiB, overlays X tail
    //   after QKV) | Wb @136MiB
    // d_out: vT (24MiB, transposed v from QKV) | psums @24MiB (2MB) -> both dead before
    //   the final f32 output overwrites d_out.
    char* ws = (char*)d_ws;
    ushort_t* q    = (ushort_t*)(ws);
    ushort_t* att  = q;                        // PV overwrites q after scores consumed it
    ushort_t* k    = (ushort_t*)(ws + 25165824ll);
    ushort_t* h    = k;                        // k dead after scores
    ushort_t* X    = (ushort_t*)(ws + 50331648ll);  // 3 x 24MiB
    ushort_t* P    = (ushort_t*)(ws + 75497472ll);  // overlays X[1..2] after QKV
    ushort_t* Wb   = (ushort_t*)(ws + 142606336ll);
    ushort_t* vT   = (ushort_t*)d_out;               // transposed v, per-batch [768][2048]
    float*  psums  = (float*)((char*)d_out + 25165824ll); // 2MB

    const int WQ = 0, WG1 = 1769472, WG2 = 2359296;
    const int BQ = 2949120, BG1 = 2951424, BG2 = 2952192, TSO = 2952960;

    const dim3 blk(256);
    const float scale = 0.03608439182435161f; // 1/sqrt(768)

    // 0. convert inputs + params to bf16 (single launch)
    convert_all<<<dim3(INBLK + (NTOT / 8 + 255) / 256), blk, 0, stream>>>(
        query, key_, value, Wq, Wk, Wv, Wg1, Wg2, bq, bk, bv, bg1, bg2, tsc, X, Wb);
    // 1. fused QKV projections: bz=0->q, 1->k, 2->vT (d_out, LDS-staged transposed write)
    gemm_bt<1, 0, 1><<<dim3(D / 128, MS / 128, 3), blk, 0, stream>>>(
        X, Wb + WQ, q, vT, Wb + BQ, nullptr, nullptr, nullptr,
        MS, D, D, 1.f, MSD, (long long)WSEG, MSD);
    // 2. P = exp(q @ k^T * scale), + per-block row partials -> psums (d_out tail); X dead
    gemm_bt<5, 0, 0><<<dim3(S / 128, S / 128, Bc), blk, 0, stream>>>(
        q, k, P, nullptr, nullptr, nullptr, nullptr, psums,
        S, S, D, scale, SD, SD, SS);
    // 3. att = (P @ vT^T) / rowsum   (rinv computed in-prologue from psums; att overlays q)
    gemm_bt<7, 0, 0><<<dim3(D / 128, S / 128, Bc), blk, 0, stream>>>(
        P, vT, att, nullptr, nullptr, nullptr, nullptr, psums,
        S, D, S, 1.f, SS, SD, SD);
    // 4. h = relu(att @ Wg1^T + bg1)  (h overlays k)
    gemm_bt<3, 0, 0><<<dim3(D / 128, MS / 128, 1), blk, 0, stream>>>(
        att, Wb + WG1, h, nullptr, Wb + BG1, nullptr, nullptr, nullptr,
        MS, D, D, 1.f, 0, 0, 0);
    // 5. out = sigmoid(sigmoid(h @ Wg2^T + bg2)) * att * ts  (f32 -> d_out, clobbers vT+psums)
    gemm_bt<4, 1, 0><<<dim3(D / 128, MS / 128, 1), blk, 0, stream>>>(
        h, Wb + WG2, d_out, nullptr, Wb + BG2, att, Wb + TSO, nullptr,
        MS, D, D, 1.f, 0, 0, 0);
}

// Round 16
// 321.448 us; speedup vs baseline: 1.0315x; 1.0315x over previous
//
#include <hip/hip_runtime.h>

typedef unsigned short ushort_t;
typedef __bf16 bf16x8 __attribute__((ext_vector_type(8)));
typedef float f32x4 __attribute__((ext_vector_type(4)));
typedef short short8 __attribute__((ext_vector_type(8)));
typedef short short4v __attribute__((ext_vector_type(4)));

#define SBAR()   asm volatile("s_barrier" ::: "memory")
#define WAITV0() asm volatile("s_waitcnt vmcnt(0)" ::: "memory")
#define WAITV4() asm volatile("s_waitcnt vmcnt(4)" ::: "memory")
#define WAITV8() asm volatile("s_waitcnt vmcnt(8)" ::: "memory")

__device__ __forceinline__ float bf2f(unsigned short u) {
    union { unsigned int i; float f; } v; v.i = ((unsigned int)u) << 16; return v.f;
}
__device__ __forceinline__ unsigned short f2bf(float f) {
    union { float f; unsigned int i; } v; v.f = f;
    unsigned int r = v.i + 0x7fffu + ((v.i >> 16) & 1u);
    return (unsigned short)(r >> 16);
}
__device__ __forceinline__ float sigm(float x) { return 1.0f / (1.0f + __expf(-x)); }

__device__ __forceinline__ void async_copy16(const ushort_t* src, ushort_t* dst_lds) {
    __builtin_amdgcn_global_load_lds(
        (const __attribute__((address_space(1))) void*)src,
        (__attribute__((address_space(3))) void*)dst_lds,
        16, 0, 0);
}

// ---- merged f32->bf16 conversion: inputs (q,k,v -> X) + params (5W+5b+ts -> Wb) ----
#define WSEG 589824           // 768*768
#define NWALL 2949120         // 5*WSEG
#define NTOT 2953728          // + 6*768
#define PERT 12582912ll       // 16384*768
#define INBLK 18432           // 3*PERT/8/256
__global__ __launch_bounds__(256)
void convert_all(const float* __restrict__ qi, const float* __restrict__ ki,
                 const float* __restrict__ vi,
                 const float* __restrict__ Wq, const float* __restrict__ Wk,
                 const float* __restrict__ Wv, const float* __restrict__ Wg1,
                 const float* __restrict__ Wg2, const float* __restrict__ bq,
                 const float* __restrict__ bk, const float* __restrict__ bv,
                 const float* __restrict__ bg1, const float* __restrict__ bg2,
                 const float* __restrict__ ts,
                 ushort_t* __restrict__ X, ushort_t* __restrict__ Wb)
{
    if (blockIdx.x < INBLK) {
        long long i = ((long long)blockIdx.x * 256 + threadIdx.x) * 8;
        const float* src; long long off;
        if (i < PERT)          { src = qi; off = i; }
        else if (i < 2 * PERT) { src = ki; off = i - PERT; }
        else                   { src = vi; off = i - 2 * PERT; }
        float4 a = *(const float4*)(src + off);
        float4 b = *(const float4*)(src + off + 4);
        short8 o;
        o[0] = (short)f2bf(a.x); o[1] = (short)f2bf(a.y); o[2] = (short)f2bf(a.z); o[3] = (short)f2bf(a.w);
        o[4] = (short)f2bf(b.x); o[5] = (short)f2bf(b.y); o[6] = (short)f2bf(b.z); o[7] = (short)f2bf(b.w);
        *(short8*)(X + i) = o;
    } else {
        int e = ((blockIdx.x - INBLK) * 256 + threadIdx.x) * 8;
        if (e >= NTOT) return;
        const float* src; int off;
        if (e < NWALL) {
            int wi = e / WSEG; off = e - wi * WSEG;
            src = (wi == 0) ? Wq : (wi == 1) ? Wk : (wi == 2) ? Wv : (wi == 3) ? Wg1 : Wg2;
        } else {
            int j = e - NWALL; int bi = j / 768; off = j - bi * 768;
            src = (bi == 0) ? bq : (bi == 1) ? bk : (bi == 2) ? bv : (bi == 3) ? bg1 : (bi == 4) ? bg2 : ts;
        }
        float4 a = *(const float4*)(src + off);
        float4 b = *(const float4*)(src + off + 4);
        short8 o;
        o[0] = (short)f2bf(a.x); o[1] = (short)f2bf(a.y); o[2] = (short)f2bf(a.z); o[3] = (short)f2bf(a.w);
        o[4] = (short)f2bf(b.x); o[5] = (short)f2bf(b.y); o[6] = (short)f2bf(b.z); o[7] = (short)f2bf(b.w);
        *(short8*)(Wb + e) = o;
    }
}

// C[M,N] = A[M,K] @ B[N,K]^T (+ epilogue), optionally batched (M = rows per batch).
// All-bf16 operands via global_load_lds; 3-buffer 2-deep counted-vmcnt pipeline, raw s_barrier.
// CF32: f32 store. QKV: gridDim.z=3; bz=0/1 -> Cv+bz*batchC (row-major), bz=2 -> Cv2 in
// TRANSPOSED per-batch layout vT[z][col][row] (z=row>>11); bias+bz*768.
// EPI: 0=plain, 1=+bias, 3=+bias+relu, 4=gate sigmoid(sigmoid(x+bias))*aux*ts,
//      5=exp(x*scale) + per-block row partial sums -> psum_out[bz*M+row][gridDim.x],
//      7=multiply by 1/rowsum computed in-prologue from psum_out (16 partials/row)
// Requires gridDim.x*gridDim.y*gridDim.z % 8 == 0, K%32==0, K>=64.
template<int EPI, int CF32, int QKV>
__global__ __launch_bounds__(256, 2)
void gemm_bt(const ushort_t* __restrict__ A, const ushort_t* __restrict__ B,
             void* __restrict__ Cv, void* __restrict__ Cv2,
             const ushort_t* __restrict__ bias,
             const ushort_t* __restrict__ aux, const ushort_t* __restrict__ ts,
             float* __restrict__ psum_out,
             int M, int N, int K, float scale,
             long long batchA, long long batchB, long long batchC)
{
    __shared__ __align__(16) ushort_t As[3][128 * 32];
    __shared__ __align__(16) ushort_t Bs[3][128 * 32];
    __shared__ float rsmx[256];
    const int tid  = threadIdx.x;
    const int lane = tid & 63;
    const int wave = tid >> 6;
    const int wr = wave >> 1, wc = wave & 1;

    // XCD-aware bijective swizzle over the full flat grid (nwg % 8 == 0)
    const int gx = gridDim.x, gy = gridDim.y;
    const int nwg = gx * gy * gridDim.z;
    int fid = (blockIdx.z * gy + blockIdx.y) * gx + blockIdx.x;
    fid = (fid & 7) * (nwg >> 3) + (fid >> 3);
    const int bz  = fid / (gx * gy);
    const int rem = fid - bz * (gx * gy);
    const int by  = rem / gx;
    const int bx  = rem - by * gx;
    const int row0 = by * 128;
    const int col0 = bx * 128;

    // EPI=7: per-block rinv for its 128 rows from psums (16 = scores gridDim.x = S/128).
    if (EPI == 7) {
        if (tid < 128) {
            const float* pp = psum_out + ((size_t)bz * M + row0 + tid) * 16;
            float s = 0.f;
            #pragma unroll
            for (int i = 0; i < 16; ++i) s += pp[i];
            rsmx[tid] = 1.0f / s;
        }
        __syncthreads();
    }

    f32x4 acc[4][4] = {};

    // staging: 256 threads x 16B = 64 rows of 32 bf16 per inst
    const int srow = tid >> 2;
    const int scol = (tid & 3) * 8;
    const ushort_t* ga0 = A + batchA * bz + (size_t)(row0 + srow) * K + scol;
    const ushort_t* gb0 = B + batchB * bz + (size_t)(col0 + srow) * K + scol;

    const int kop  = (lane >> 4) * 8;
    const int arow = wr * 64 + (lane & 15);
    const int brow = wc * 64 + (lane & 15);

    const int NT = K >> 5;

#define STAGE4(T, BUF) do { const int kk_ = (T) * 32; \
    async_copy16(ga0 + kk_,                  &As[BUF][0] + tid * 8); \
    async_copy16(ga0 + (size_t)64 * K + kk_, &As[BUF][0] + 2048 + tid * 8); \
    async_copy16(gb0 + kk_,                  &Bs[BUF][0] + tid * 8); \
    async_copy16(gb0 + (size_t)64 * K + kk_, &Bs[BUF][0] + 2048 + tid * 8); \
} while (0)

    STAGE4(0, 0);
    STAGE4(1, 1);

    int cur = 0;
    for (int t = 0; t < NT; ++t) {
        if (t + 2 < NT) {
            int nb = cur + 2; if (nb >= 3) nb -= 3;
            STAGE4(t + 2, nb);
            WAITV8();   // tile t landed; tiles t+1, t+2 (8 loads) in flight
        } else if (t + 1 < NT) {
            WAITV4();   // tile t landed; tile t+1 in flight
        } else {
            WAITV0();
        }
        SBAR();
        const ushort_t* Ac = &As[0][0] + cur * 4096;
        const ushort_t* Bc = &Bs[0][0] + cur * 4096;
        bf16x8 af[4], bfr[4];
        #pragma unroll
        for (int m = 0; m < 4; ++m)
            af[m] = *(const bf16x8*)(Ac + (arow + m * 16) * 32 + kop);
        #pragma unroll
        for (int n = 0; n < 4; ++n)
            bfr[n] = *(const bf16x8*)(Bc + (brow + n * 16) * 32 + kop);
        #pragma unroll
        for (int m = 0; m < 4; ++m)
            #pragma unroll
            for (int n = 0; n < 4; ++n)
                acc[m][n] = __builtin_amdgcn_mfma_f32_16x16x32_bf16(af[m], bfr[n], acc[m][n], 0, 0, 0);
        SBAR();
        ++cur; if (cur >= 3) cur = 0;
    }
#undef STAGE4

    // epilogue: C/D layout col=lane&15, row=(lane>>4)*4+reg
    const int r0 = row0 + wr * 64 + (lane >> 4) * 4;
    const int c0 = col0 + wc * 64 + (lane & 15);

    float rv[4][4];
    if (EPI == 7) {
        #pragma unroll
        for (int m = 0; m < 4; ++m)
            #pragma unroll
            for (int r = 0; r < 4; ++r)
                rv[m][r] = rsmx[wr * 64 + m * 16 + (lane >> 4) * 4 + r];
    }
    float rsum[4][4] = {};

    if (QKV && bz == 2) {
        // v written TRANSPOSED: vT[z][col][row], z = row>>11, r = row&2047.
        // 4 consecutive r per (m,n) -> one 8B short4 store.
        ushort_t* vT = (ushort_t*)Cv2 + ((size_t)(row0 >> 11)) * 1572864ll;
        #pragma unroll
        for (int m = 0; m < 4; ++m) {
            const int rr = (r0 + m * 16) & 2047;
            #pragma unroll
            for (int n = 0; n < 4; ++n) {
                const int col = c0 + n * 16;
                const float bv_ = bf2f(bias[2 * 768 + col]);
                short4v o;
                #pragma unroll
                for (int r = 0; r < 4; ++r)
                    o[r] = (short)f2bf(acc[m][n][r] + bv_);
                *(short4v*)(vT + (size_t)col * 2048 + rr) = o;
            }
        }
        return;
    }

    ushort_t* Cb = (ushort_t*)Cv + batchC * bz;
    float* Cf = (float*)Cv;
    #pragma unroll
    for (int m = 0; m < 4; ++m) {
        #pragma unroll
        for (int n = 0; n < 4; ++n) {
            const int col = c0 + n * 16;
            #pragma unroll
            for (int r = 0; r < 4; ++r) {
                const int row = r0 + m * 16 + r;
                float val = acc[m][n][r];
                if (EPI == 1) {
                    val += bf2f(bias[(QKV ? bz * 768 : 0) + col]);
                } else if (EPI == 3) {
                    val += bf2f(bias[col]);
                    val = fmaxf(val, 0.0f);
                } else if (EPI == 4) {
                    val += bf2f(bias[col]);
                    float g  = sigm(val);
                    float gg = sigm(g);
                    val = gg * bf2f(aux[(size_t)row * N + col]) * bf2f(ts[col]);
                } else if (EPI == 5) {
                    val = __expf(val * scale);
                    rsum[m][r] += val;
                } else if (EPI == 7) {
                    val *= rv[m][r];
                }
                if (CF32) Cf[(size_t)row * N + col] = val;
                else      Cb[(size_t)row * N + col] = f2bf(val);
            }
        }
    }

    if (EPI == 5) {
        // reduce over the 16 lanes holding the wave's 16-col groups (lane bits 0..3)
        #pragma unroll
        for (int m = 0; m < 4; ++m)
            #pragma unroll
            for (int r = 0; r < 4; ++r) {
                float s = rsum[m][r];
                s += __shfl_xor(s, 1);
                s += __shfl_xor(s, 2);
                s += __shfl_xor(s, 4);
                s += __shfl_xor(s, 8);
                rsum[m][r] = s;
            }
        if ((lane & 15) == 0) {
            const int quad = lane >> 4;
            #pragma unroll
            for (int m = 0; m < 4; ++m)
                #pragma unroll
                for (int r = 0; r < 4; ++r)
                    rsmx[(wr * 64 + m * 16 + quad * 4 + r) * 2 + wc] = rsum[m][r];
        }
        __syncthreads();
        if (tid < 128) {
            float s = rsmx[tid * 2] + rsmx[tid * 2 + 1];
            psum_out[((size_t)bz * M + row0 + tid) * gx + bx] = s;
        }
    }
}

extern "C" void kernel_launch(void* const* d_in, const int* in_sizes, int n_in,
                              void* d_out, int out_size, void* d_ws, size_t ws_size,
                              hipStream_t stream)
{
    (void)in_sizes; (void)n_in; (void)out_size; (void)ws_size;
    const float* query = (const float*)d_in[0];
    const float* key_  = (const float*)d_in[1];
    const float* value = (const float*)d_in[2];
    const float* Wq  = (const float*)d_in[3];
    const float* bq  = (const float*)d_in[4];
    const float* Wk  = (const float*)d_in[5];
    const float* bk  = (const float*)d_in[6];
    const float* Wv  = (const float*)d_in[7];
    const float* bv  = (const float*)d_in[8];
    const float* Wg1 = (const float*)d_in[9];
    const float* bg1 = (const float*)d_in[10];
    const float* Wg2 = (const float*)d_in[11];
    const float* bg2 = (const float*)d_in[12];
    const float* tsc = (const float*)d_in[13];

    const int S = 2048, D = 768, Bc = 8;
    const int MS = Bc * S;                     // 16384
    const long long SD = (long long)S * D;     // 1,572,864
    const long long SS = (long long)S * S;     // 4,194,304
    const long long MSD = (long long)MS * D;   // 12,582,912

    // ws layout (bytes):
    //   q/att @0 (24MiB) | k/h @24MiB | X @48MiB (72MiB) | P @72MiB (64MiB, overlays X tail
    //   after QKV) | Wb @136MiB
    // d_out: vT (24MiB, written transposed by QKV) | psums @24MiB (2MB) -> both dead before
    //   the final f32 output overwrites d_out.
    char* ws = (char*)d_ws;
    ushort_t* q    = (ushort_t*)(ws);
    ushort_t* att  = q;                        // PV overwrites q after scores consumed it
    ushort_t* k    = (ushort_t*)(ws + 25165824ll);
    ushort_t* h    = k;                        // k dead after scores
    ushort_t* X    = (ushort_t*)(ws + 50331648ll);  // 3 x 24MiB
    ushort_t* P    = (ushort_t*)(ws + 75497472ll);  // overlays X[1..2] after QKV
    ushort_t* Wb   = (ushort_t*)(ws + 142606336ll);
    ushort_t* vT   = (ushort_t*)d_out;               // transposed v, per-batch [768][2048]
    float*  psums  = (float*)((char*)d_out + 25165824ll); // 2MB

    const int WQ = 0, WG1 = 1769472, WG2 = 2359296;
    const int BQ = 2949120, BG1 = 2951424, BG2 = 2952192, TSO = 2952960;

    const dim3 blk(256);
    const float scale = 0.03608439182435161f; // 1/sqrt(768)

    // 0. convert inputs + params to bf16 (single launch)
    convert_all<<<dim3(INBLK + (NTOT / 8 + 255) / 256), blk, 0, stream>>>(
        query, key_, value, Wq, Wk, Wv, Wg1, Wg2, bq, bk, bv, bg1, bg2, tsc, X, Wb);
    // 1. fused QKV projections: bz=0->q, 1->k, 2->vT (d_out, transposed write)
    gemm_bt<1, 0, 1><<<dim3(D / 128, MS / 128, 3), blk, 0, stream>>>(
        X, Wb + WQ, q, vT, Wb + BQ, nullptr, nullptr, nullptr,
        MS, D, D, 1.f, MSD, (long long)WSEG, MSD);
    // 2. P = exp(q @ k^T * scale), + per-block row partials -> psums (d_out tail); X dead
    gemm_bt<5, 0, 0><<<dim3(S / 128, S / 128, Bc), blk, 0, stream>>>(
        q, k, P, nullptr, nullptr, nullptr, nullptr, psums,
        S, S, D, scale, SD, SD, SS);
    // 3. att = (P @ vT^T) / rowsum   (rinv computed in-prologue from psums; att overlays q)
    gemm_bt<7, 0, 0><<<dim3(D / 128, S / 128, Bc), blk, 0, stream>>>(
        P, vT, att, nullptr, nullptr, nullptr, nullptr, psums,
        S, D, S, 1.f, SS, SD, SD);
    // 4. h = relu(att @ Wg1^T + bg1)  (h overlays k)
    gemm_bt<3, 0, 0><<<dim3(D / 128, MS / 128, 1), blk, 0, stream>>>(
        att, Wb + WG1, h, nullptr, Wb + BG1, nullptr, nullptr, nullptr,
        MS, D, D, 1.f, 0, 0, 0);
    // 5. out = sigmoid(sigmoid(h @ Wg2^T + bg2)) * att * ts  (f32 -> d_out, clobbers vT+psums)
    gemm_bt<4, 1, 0><<<dim3(D / 128, MS / 128, 1), blk, 0, stream>>>(
        h, Wb + WG2, d_out, nullptr, Wb + BG2, att, Wb + TSO, nullptr,
        MS, D, D, 1.f, 0, 0, 0);
}